// Round 6
// baseline (910.887 us; speedup 1.0000x reference)
//
#include <hip/hip_runtime.h>
#include <math.h>

// ---------------------------------------------------------------------------
// MFMA round, fp16 2-term scheme. fp32 outputs. Per-array dtype detection
// (bf16/fp32/zero). All three MLPs: A split into fp16 hi/lo planes, B rounded
// to a single fp16 plane; a*b ~= alo*b + ahi*b (error ~ a*blo, |blo|<=|b|*2^-12;
// with 0.02-scale weights the per-output bound is ~3e-5). Top-8 correctness vs
// fp64 reference guaranteed by a margin-gated fp64 rescue pass (MARGIN=2e-4,
// ~6 sigma of the fp16-2term error bound).
// vs prior bf16 3-term/2-plane: MFMA count x2/3, B-plane L2 bytes x1/2.
// MROWS=32, 2 blocks/CU, unpadded LDS + 4-bit XOR swizzle (conflict-free).
// ---------------------------------------------------------------------------

typedef _Float16 halfx8 __attribute__((ext_vector_type(8)));
typedef float    floatx4 __attribute__((ext_vector_type(4)));
#define MFMA16(a,b,c) __builtin_amdgcn_mfma_f32_16x16x32_f16((a),(b),(c),0,0,0)

#define BN 65536
#define MROWS 32
#define MARGIN 2e-4f

// LDS layout (per block, 81920 B total -> 2 blocks/CU on 160 KiB LDS):
//   [0,      8192)  ix hi plane (32 rows x 256 B, swizzled, fp16)
//   [8192,  16384)  ix lo plane
//   [16384, 49152)  h  hi plane (32 rows x 1024 B, swizzled, fp16)
//   [49152, 81920)  h  lo plane
//   outb (SUB only) aliases [0, 8448): 32 x 66 f32 (ix dead after layer 1)
#define SM_IX0 0
#define SM_IX1 8192
#define SM_H0  16384
#define SM_H1  49152
#define SM_BYTES 81920
#define OBST 66

// packed single-plane sizes/offsets (fp16 elements)
#define SZ_W1 65536
#define SZ_W2 262144
#define SZ_WD 32768
#define SZ_ATT 16384
#define OFF_SW1 0
#define OFF_SW2 (OFF_SW1 + SZ_W1)
#define OFF_SWD (OFF_SW2 + SZ_W2)
#define OFF_MW1 (OFF_SWD + SZ_WD)
#define OFF_MW2 (OFF_MW1 + SZ_W1)
#define OFF_MWD (OFF_MW2 + SZ_W2)
#define OFF_FW1 (OFF_MWD + SZ_WD)
#define OFF_FW2 (OFF_FW1 + SZ_W1)
#define OFF_FWD (OFF_FW2 + SZ_W2)
#define OFF_ATT (OFF_FWD + SZ_WD)

// ws byte offsets (pack ends at ~2.2 MB)
#define WS_MASKS (5u << 20)     // BN * 8 B
#define WS_RROWS (6u << 20)     // up to BN ints
#define WS_RCNT  (7u << 20)     // 1 int
#define WS_FLAGS ((7u << 20) + 256)

enum { R_X = 0, R_Y, R_SW1, R_SB1, R_SW2, R_SB2, R_SWD, R_SBD,
       R_MW1, R_MB1, R_MW2, R_MB2, R_MWD, R_MBD, R_ATTW, R_ATTB,
       R_FW1, R_FB1, R_FW2, R_FB2, R_FWD, R_FBD, N_ROLES };

__device__ __forceinline__ float bf2f(unsigned short u) {
    return __uint_as_float((unsigned)u << 16);
}
// fl: 1=bf16, 0=fp32, 2=zero
__device__ __forceinline__ float loadf(const void* p, size_t i, int fl) {
    return fl == 1 ? bf2f(((const unsigned short*)p)[i])
         : fl == 0 ? ((const float*)p)[i] : 0.f;
}
__device__ __forceinline__ double loadd(const void* p, size_t i, int fl) {
    return fl == 1 ? (double)bf2f(((const unsigned short*)p)[i])
         : fl == 0 ? (double)((const float*)p)[i] : 0.0;
}
// compile-time-flag variant: branch-free loop bodies in the rescue kernel
template<int FL>
__device__ __forceinline__ double ldw(const void* p, size_t i) {
    return FL == 1 ? (double)bf2f(((const unsigned short*)p)[i])
         : FL == 0 ? (double)((const float*)p)[i] : 0.0;
}
struct hf2 { _Float16 hi, lo; };
__device__ __forceinline__ hf2 split2h(float v) {
    hf2 r;
    r.hi = (_Float16)v;
    r.lo = (_Float16)(v - (float)r.hi);
    return r;
}
// LDS swizzle: byte offset within a plane; rsB = 256 (ix) or 1024 (h).
__device__ __forceinline__ int swz(int row, int colB, int rsB) {
    return (row * rsB + colB) ^ ((row & 15) << 4);
}

// B-fragment load: 4 nt-tiles (single fp16 plane) for one kt.
__device__ __forceinline__ void ld_b4(const _Float16* __restrict__ p,
                                      int base, int ktn, int kt, int l,
                                      halfx8 (&b)[4])
{
#pragma unroll
    for (int nt = 0; nt < 4; ++nt) {
        const size_t fi = ((((size_t)(base + nt)) * ktn + kt) * 64 + l) * 8;
        b[nt] = *(const halfx8*)(p + fi);
    }
}

// One kt of MFMA work: read A hi/lo frags from LDS, 2-term MFMA into acc.
__device__ __forceinline__ void kt_mfma(const char* __restrict__ sm,
                                        int smA0, int smA1, int rsB,
                                        int kt, int l15, int q,
                                        const halfx8 (&b)[4],
                                        floatx4 (&acc)[2][4])
{
    const int cB = kt * 64 + q * 16;
    halfx8 ahi[2], alo[2];
#pragma unroll
    for (int rt = 0; rt < 2; ++rt) {
        const int off = swz(rt * 16 + l15, cB, rsB);
        ahi[rt] = *(const halfx8*)(sm + smA0 + off);
        alo[rt] = *(const halfx8*)(sm + smA1 + off);
    }
#pragma unroll
    for (int nt = 0; nt < 4; ++nt)
#pragma unroll
        for (int rt = 0; rt < 2; ++rt) {
            acc[rt][nt] = MFMA16(alo[rt], b[nt], acc[rt][nt]);
            acc[rt][nt] = MFMA16(ahi[rt], b[nt], acc[rt][nt]);
        }
}

// ---------------------------------------------------------------------------
// detect: per-array dtype (1=bf16, 0=fp32, 2=zero). Also zeroes rescue count.
// ---------------------------------------------------------------------------
struct DetArgs { const void* p[N_ROLES]; int n[N_ROLES]; };

__global__ __launch_bounds__(256) void detect_kernel(DetArgs da, int* flags, int* rcnt) {
    const int role = blockIdx.x;
    if (role == 0 && threadIdx.x == 0) *rcnt = 0;
    const unsigned short* u = (const unsigned short*)da.p[role];
    int nsamp = da.n[role] / 2;
    if (nsamp > 4096) nsamp = 4096;
    __shared__ int band, nz;
    if (threadIdx.x == 0) { band = 0; nz = 0; }
    __syncthreads();
    int lb = 0, lnz = 0;
    for (int i = threadIdx.x; i < nsamp; i += 256) {
        const unsigned short v = u[2 * i];
        if (v) {
            ++lnz;
            const int e = (v >> 7) & 0xFF;
            if (e >= 100 && e <= 126) ++lb;
        }
    }
    atomicAdd(&band, lb);
    atomicAdd(&nz, lnz);
    __syncthreads();
    if (threadIdx.x == 0)
        flags[role] = (nz == 0) ? 2 : ((band * 2 > nz) ? 1 : 0);
}

// ---------------------------------------------------------------------------
// pack: [K x N] -> MFMA B-frag single fp16 plane. Frag for tile (kt,nt):
// lane l, j=0..7 holds W[kt*32 + (l>>4)*8 + j][nt*16 + (l&15)].
// ---------------------------------------------------------------------------
struct PackArgs { const void* src[10]; int K[10], N[10], off[10], role[10]; };

__global__ __launch_bounds__(256) void pack_weights(PackArgs pa, _Float16* dst,
                                                    const int* __restrict__ flags) {
    const int m = blockIdx.y;
    const int fl = flags[pa.role[m]];
    const int K = pa.K[m], N = pa.N[m];
    const int KT = K >> 5, NT = N >> 4;
    const int total = KT * NT * 64;
    const int t = blockIdx.x * 256 + threadIdx.x;
    if (t >= total) return;
    const int l = t & 63;
    const int idx = t >> 6;            // nt*KT + kt
    const int kt = idx % KT;
    const int nt = idx / KT;
    const int k0 = kt * 32 + ((l >> 4) << 3);
    const int n  = nt * 16 + (l & 15);
    _Float16* dh = dst + pa.off[m] + (size_t)t * 8;
#pragma unroll
    for (int j = 0; j < 8; ++j)
        dh[j] = (_Float16)loadf(pa.src[m], (size_t)(k0 + j) * N + n, fl);
}

// ---------------------------------------------------------------------------
// Core 3-layer MFMA MLP (32 rows, 512 threads = 8 waves, 2 row-tiles/wave).
// fp16 2-term; A from swizzled LDS planes; h in-place; fp32 out.
// ---------------------------------------------------------------------------
template <bool SUB>
__device__ __forceinline__ void mlp_core(
    char* __restrict__ sm,
    const _Float16* __restrict__ p1,
    const _Float16* __restrict__ p2,
    const _Float16* __restrict__ pd,
    const void* __restrict__ b1, int fb1,
    const void* __restrict__ b2, int fb2,
    const void* __restrict__ bd, int fbd,
    int r0, float* __restrict__ out)
{
    const int tid = threadIdx.x;
    const int l = tid & 63, w = tid >> 6, l15 = l & 15, q = l >> 4;

    // ---- layer 1: K=128, N=512; wave w owns 64-col slab; 2 row-tiles ----
    floatx4 acc[2][4];
#pragma unroll
    for (int rt = 0; rt < 2; ++rt)
#pragma unroll
        for (int nt = 0; nt < 4; ++nt) acc[rt][nt] = (floatx4)0.0f;
#pragma unroll
    for (int kt = 0; kt < 4; ++kt) {
        halfx8 B[4];
        ld_b4(p1, w * 4, 4, kt, l, B);
        kt_mfma(sm, SM_IX0, SM_IX1, 256, kt, l15, q, B, acc);
    }
#pragma unroll
    for (int nt = 0; nt < 4; ++nt) {
        const int col = w * 64 + nt * 16 + l15;
        const float bias = loadf(b1, col, fb1);
#pragma unroll
        for (int rt = 0; rt < 2; ++rt)
#pragma unroll
            for (int r = 0; r < 4; ++r) {
                const int row = rt * 16 + q * 4 + r;
                float v = acc[rt][nt][r] + bias;
                v = v > 0.f ? v : 0.f;
                const hf2 s = split2h(v);
                const int o = swz(row, col * 2, 1024);
                *(_Float16*)(sm + SM_H0 + o) = s.hi;
                *(_Float16*)(sm + SM_H1 + o) = s.lo;
            }
    }
    __syncthreads();

    // ---- layer 2: K=512, in-place ----
    floatx4 acc2[2][4];
#pragma unroll
    for (int rt = 0; rt < 2; ++rt)
#pragma unroll
        for (int nt = 0; nt < 4; ++nt) acc2[rt][nt] = (floatx4)0.0f;
    for (int kt = 0; kt < 16; ++kt) {
        halfx8 B[4];
        ld_b4(p2, w * 4, 16, kt, l, B);
        kt_mfma(sm, SM_H0, SM_H1, 1024, kt, l15, q, B, acc2);
    }
    __syncthreads();  // all reads of h done before overwrite
#pragma unroll
    for (int nt = 0; nt < 4; ++nt) {
        const int col = w * 64 + nt * 16 + l15;
        const float bias = loadf(b2, col, fb2);
#pragma unroll
        for (int rt = 0; rt < 2; ++rt)
#pragma unroll
            for (int r = 0; r < 4; ++r) {
                const int row = rt * 16 + q * 4 + r;
                float v = acc2[rt][nt][r] + bias;
                v = v > 0.f ? v : 0.f;
                const hf2 s = split2h(v);
                const int o = swz(row, col * 2, 1024);
                *(_Float16*)(sm + SM_H0 + o) = s.hi;
                *(_Float16*)(sm + SM_H1 + o) = s.lo;
            }
    }
    __syncthreads();

    // ---- layer 3: K=512, N=64; 8 waves: nt=w&3, rt=w>>2 ----
    {
        const int nt3 = w & 3, rt3 = w >> 2;
        floatx4 a3 = (floatx4)0.0f;
        for (int kt = 0; kt < 16; ++kt) {
            const size_t fi = (((size_t)(nt3 * 16 + kt)) * 64 + l) * 8;
            const halfx8 b = *(const halfx8*)(pd + fi);
            const int off = swz(rt3 * 16 + l15, kt * 64 + q * 16, 1024);
            const halfx8 ahi = *(const halfx8*)(sm + SM_H0 + off);
            const halfx8 alo = *(const halfx8*)(sm + SM_H1 + off);
            a3 = MFMA16(alo, b, a3);
            a3 = MFMA16(ahi, b, a3);
        }
        const int col = nt3 * 16 + l15;
        const float bias = loadf(bd, col, fbd);
        float* outb = (float*)sm;  // aliases ix region (dead after L1)
#pragma unroll
        for (int r = 0; r < 4; ++r) {
            const int row = rt3 * 16 + q * 4 + r;
            const float v = a3[r] + bias;  // no relu on output layer
            out[(size_t)(r0 + row) * 64 + col] = v;
            if (SUB) outb[row * OBST + col] = v;
        }
    }
    if (SUB) __syncthreads();
}

// ---------------------------------------------------------------------------
// K1: sub MLP + per-row top-8 mask + margin-gated rescue list.
// ---------------------------------------------------------------------------
__global__ __launch_bounds__(512, 4)
void sub_mfma(const void* __restrict__ x, const _Float16* __restrict__ wpack,
              const void* __restrict__ b1, const void* __restrict__ b2,
              const void* __restrict__ bd, const int* __restrict__ flags,
              float* __restrict__ out, unsigned long long* __restrict__ masks,
              int* __restrict__ rrows, int* __restrict__ rcnt)
{
    __shared__ __align__(16) char sm[SM_BYTES];
    const int fx = flags[R_X];
    const int r0 = blockIdx.x * MROWS;

    for (int i = threadIdx.x; i < MROWS * 128; i += 512) {
        const int r = i >> 7, c = i & 127;
        const hf2 s = split2h(loadf(x, (size_t)(r0 + r) * 128 + c, fx));
        const int off = swz(r, c * 2, 256);
        *(_Float16*)(sm + SM_IX0 + off) = s.hi;
        *(_Float16*)(sm + SM_IX1 + off) = s.lo;
    }
    __syncthreads();

    mlp_core<true>(sm, wpack + OFF_SW1, wpack + OFF_SW2, wpack + OFF_SWD,
                   b1, flags[R_SB1], b2, flags[R_SB2], bd, flags[R_SBD],
                   r0, out);

    // top-9 per row (strict '>' insertion: jax tie rule -> lowest index wins)
    if (threadIdx.x < MROWS) {
        const float* rowp = (const float*)sm + threadIdx.x * OBST;
        float vals[9];
        int idxs[9];
#pragma unroll
        for (int j = 0; j < 9; ++j) { vals[j] = -__builtin_inff(); idxs[j] = 0; }
        for (int i = 0; i < 64; ++i) {
            const float v = rowp[i];
            if (v > vals[8]) {
                int p = 8;
                while (p > 0 && v > vals[p - 1]) {
                    vals[p] = vals[p - 1];
                    idxs[p] = idxs[p - 1];
                    --p;
                }
                vals[p] = v;
                idxs[p] = i;
            }
        }
        unsigned long long m = 0ull;
#pragma unroll
        for (int j = 0; j < 8; ++j) m |= (1ull << idxs[j]);
        masks[r0 + threadIdx.x] = m;
        if (vals[7] - vals[8] < MARGIN) {
            const int slot = atomicAdd(rcnt, 1);
            rrows[slot] = r0 + threadIdx.x;
        }
    }
}

// ---------------------------------------------------------------------------
// K1b: fp64 rescue for marginal rows — recompute sub rows exactly, fix mask
// and out_sub rows. Batched: 16 rows per block-iteration staged in LDS so
// each weight element is loaded once and FMA'd into 16 row-accumulators.
// ---------------------------------------------------------------------------
#define RPB 16
#define XST 130    // xs row stride (128 + 2)
#define HST2 516   // h row stride (512 + 4)

// L1/L2: 256 threads own cols (t, t+256); accumulate 16 rows each.
template<int FL, int K, int S>
__device__ __forceinline__ void r_layer12(const void* __restrict__ W,
                                          const double* __restrict__ in,
                                          double* __restrict__ a0,
                                          double* __restrict__ a1, int t)
{
    for (int k = 0; k < K; ++k) {
        const double w0 = ldw<FL>(W, (size_t)k * 512 + t);
        const double w1 = ldw<FL>(W, (size_t)k * 512 + t + 256);
#pragma unroll
        for (int r = 0; r < RPB; ++r) {
            a0[r] = fma(in[r * S + k], w0, a0[r]);
            a1[r] = fma(in[r * S + k], w1, a1[r]);
        }
    }
}

// L3: thread owns col c = t&63, row-group rg = t>>6 (4 rows).
template<int FL>
__device__ __forceinline__ void r_layer3(const void* __restrict__ W,
                                         const double* __restrict__ h,
                                         int c, int rg, double* __restrict__ a)
{
    for (int k = 0; k < 512; ++k) {
        const double w = ldw<FL>(W, (size_t)k * 64 + c);
#pragma unroll
        for (int j = 0; j < 4; ++j)
            a[j] = fma(h[(rg * 4 + j) * HST2 + k], w, a[j]);
    }
}

#define R_DISPATCH(fl, CALL)                                   \
    do {                                                       \
        if ((fl) == 1)      { CALL(1); }                       \
        else if ((fl) == 0) { CALL(0); }                       \
        else                { CALL(2); }                       \
    } while (0)

__global__ __launch_bounds__(256)
void rescue_kernel(const void* __restrict__ x,
                   const void* __restrict__ W1, const void* __restrict__ b1,
                   const void* __restrict__ W2, const void* __restrict__ b2,
                   const void* __restrict__ Wd, const void* __restrict__ bd,
                   const int* __restrict__ flags,
                   const int* __restrict__ rrows, const int* __restrict__ rcnt,
                   float* __restrict__ out, unsigned long long* __restrict__ masks)
{
    __shared__ double xs[RPB * XST];
    __shared__ double h[RPB * HST2];
    __shared__ double ob[RPB][64];
    __shared__ int rowids[RPB];
    const int fx = flags[R_X], f1 = flags[R_SW1], fb1 = flags[R_SB1],
              f2 = flags[R_SW2], fb2 = flags[R_SB2],
              f3 = flags[R_SWD], fb3 = flags[R_SBD];
    const int t = threadIdx.x;
    const int n = *rcnt;

    for (int g = blockIdx.x; g * RPB < n; g += gridDim.x) {
        const int base = g * RPB;
        int cnt = n - base;
        if (cnt > RPB) cnt = RPB;
        if (t < RPB) rowids[t] = rrows[base + (t < cnt ? t : cnt - 1)];
        __syncthreads();

        // stage inputs (fp64)
        for (int i = t; i < RPB * 128; i += 256) {
            const int r = i >> 7, c = i & 127;
            xs[r * XST + c] = loadd(x, (size_t)rowids[r] * 128 + c, fx);
        }
        __syncthreads();

        // ---- L1: K=128 ----
        {
            double a0[RPB], a1[RPB];
#pragma unroll
            for (int r = 0; r < RPB; ++r) { a0[r] = 0.0; a1[r] = 0.0; }
#define L1_CALL(FL) r_layer12<FL, 128, XST>(W1, xs, a0, a1, t)
            R_DISPATCH(f1, L1_CALL);
#undef L1_CALL
            const double bb0 = loadd(b1, t, fb1), bb1 = loadd(b1, t + 256, fb1);
#pragma unroll
            for (int r = 0; r < RPB; ++r) {
                const double v0 = a0[r] + bb0, v1 = a1[r] + bb1;
                h[r * HST2 + t]       = v0 > 0.0 ? v0 : 0.0;
                h[r * HST2 + t + 256] = v1 > 0.0 ? v1 : 0.0;
            }
        }
        __syncthreads();

        // ---- L2: K=512, in-place (accumulate fully, then overwrite) ----
        {
            double a0[RPB], a1[RPB];
#pragma unroll
            for (int r = 0; r < RPB; ++r) { a0[r] = 0.0; a1[r] = 0.0; }
#define L2_CALL(FL) r_layer12<FL, 512, HST2>(W2, h, a0, a1, t)
            R_DISPATCH(f2, L2_CALL);
#undef L2_CALL
            __syncthreads();  // all reads of h done before overwrite
            const double bb0 = loadd(b2, t, fb2), bb1 = loadd(b2, t + 256, fb2);
#pragma unroll
            for (int r = 0; r < RPB; ++r) {
                const double v0 = a0[r] + bb0, v1 = a1[r] + bb1;
                h[r * HST2 + t]       = v0 > 0.0 ? v0 : 0.0;
                h[r * HST2 + t + 256] = v1 > 0.0 ? v1 : 0.0;
            }
        }
        __syncthreads();

        // ---- L3: K=512, N=64; col c, 4 rows per thread ----
        {
            const int c = t & 63, rg = t >> 6;
            double a[4];
#pragma unroll
            for (int j = 0; j < 4; ++j) a[j] = 0.0;
#define L3_CALL(FL) r_layer3<FL>(Wd, h, c, rg, a)
            R_DISPATCH(f3, L3_CALL);
#undef L3_CALL
            const double bb = loadd(bd, c, fb3);
#pragma unroll
            for (int j = 0; j < 4; ++j) {
                const int r = rg * 4 + j;
                const double v = a[j] + bb;
                ob[r][c] = v;
                if (r < cnt) out[(size_t)rowids[r] * 64 + c] = (float)v;
            }
        }
        __syncthreads();

        // ---- top-8 per valid row (strict '>' insertion, as before) ----
        if (t < cnt) {
            double vals[8];
            int idxs[8];
#pragma unroll
            for (int j = 0; j < 8; ++j) { vals[j] = -1.0e300; idxs[j] = 0; }
            for (int i = 0; i < 64; ++i) {
                const double v = ob[t][i];
                if (v > vals[7]) {
                    int p = 7;
                    while (p > 0 && v > vals[p - 1]) {
                        vals[p] = vals[p - 1];
                        idxs[p] = idxs[p - 1];
                        --p;
                    }
                    vals[p] = v;
                    idxs[p] = i;
                }
            }
            unsigned long long m = 0ull;
#pragma unroll
            for (int j = 0; j < 8; ++j) m |= (1ull << idxs[j]);
            masks[rowids[t]] = m;
        }
        __syncthreads();  // ob/rowids/xs reused next iteration
    }
}

// ---------------------------------------------------------------------------
// K2: mm MLP from masked y.
// ---------------------------------------------------------------------------
__global__ __launch_bounds__(512, 4)
void mm_mfma(const unsigned long long* __restrict__ masks,
             const void* __restrict__ y, const _Float16* __restrict__ wpack,
             const void* __restrict__ b1, const void* __restrict__ b2,
             const void* __restrict__ bd, const int* __restrict__ flags,
             float* __restrict__ out)
{
    __shared__ __align__(16) char sm[SM_BYTES];
    const int fy = flags[R_Y];
    const int r0 = blockIdx.x * MROWS;

    for (int i = threadIdx.x; i < MROWS * 128; i += 512) {
        const int r = i >> 7, c = i & 127;
        const bool keep = (masks[r0 + r] >> (c >> 1)) & 1ull;
        const float v = keep ? loadf(y, (size_t)(r0 + r) * 128 + c, fy) : 0.f;
        const hf2 s = split2h(v);
        const int off = swz(r, c * 2, 256);
        *(_Float16*)(sm + SM_IX0 + off) = s.hi;
        *(_Float16*)(sm + SM_IX1 + off) = s.lo;
    }
    __syncthreads();

    mlp_core<false>(sm, wpack + OFF_MW1, wpack + OFF_MW2, wpack + OFF_MWD,
                    b1, flags[R_MB1], b2, flags[R_MB2], bd, flags[R_MBD],
                    r0, out);
}

// ---------------------------------------------------------------------------
// K3: cat (fp32 from d_out) -> sigmoid attention gate -> fusion MLP.
// ---------------------------------------------------------------------------
__global__ __launch_bounds__(512, 4)
void fusion_mfma(const float* __restrict__ subf, const float* __restrict__ mmf,
                 const _Float16* __restrict__ wpack,
                 const void* __restrict__ attb,
                 const void* __restrict__ b1, const void* __restrict__ b2,
                 const void* __restrict__ bd, const int* __restrict__ flags,
                 float* __restrict__ out)
{
    __shared__ __align__(16) char sm[SM_BYTES];
    const int tid = threadIdx.x;
    const int l = tid & 63, w = tid >> 6, l15 = l & 15, q = l >> 4;
    const int r0 = blockIdx.x * MROWS;

    for (int i = tid; i < MROWS * 128; i += 512) {
        const int r = i >> 7, c = i & 127;
        const size_t row = (size_t)(r0 + r);
        const float v = (c < 64) ? subf[row * 64 + c] : mmf[row * 64 + (c - 64)];
        const hf2 s = split2h(v);
        const int off = swz(r, c * 2, 256);
        *(_Float16*)(sm + SM_IX0 + off) = s.hi;
        *(_Float16*)(sm + SM_IX1 + off) = s.lo;
    }
    __syncthreads();

    // attention: N=128, wave w owns 16-col tile nt=w; 2 row-tiles; 2-term
    floatx4 aacc[2];
    aacc[0] = (floatx4)0.0f;
    aacc[1] = (floatx4)0.0f;
    const _Float16* patt = wpack + OFF_ATT;
#pragma unroll
    for (int kt = 0; kt < 4; ++kt) {
        const size_t fi = (((size_t)(w * 4 + kt)) * 64 + l) * 8;
        const halfx8 b = *(const halfx8*)(patt + fi);
        const int cB = kt * 64 + q * 16;
#pragma unroll
        for (int rt = 0; rt < 2; ++rt) {
            const int off = swz(rt * 16 + l15, cB, 256);
            const halfx8 ahi = *(const halfx8*)(sm + SM_IX0 + off);
            const halfx8 alo = *(const halfx8*)(sm + SM_IX1 + off);
            aacc[rt] = MFMA16(alo, b, aacc[rt]);
            aacc[rt] = MFMA16(ahi, b, aacc[rt]);
        }
    }
    const int col = w * 16 + l15;
    const float ab = loadf(attb, col, flags[R_ATTB]);
    float gated[2][4];
#pragma unroll
    for (int rt = 0; rt < 2; ++rt)
#pragma unroll
        for (int r = 0; r < 4; ++r) {
            const int rowl = rt * 16 + q * 4 + r;
            const float pre = aacc[rt][r] + ab;
            const float s = 1.f / (1.f + expf(-pre));
            const int off = swz(rowl, col * 2, 256);
            const float catv = (float)*(const _Float16*)(sm + SM_IX0 + off)
                             + (float)*(const _Float16*)(sm + SM_IX1 + off);
            gated[rt][r] = catv * s;
        }
    __syncthreads();  // all attention reads of ix done
#pragma unroll
    for (int rt = 0; rt < 2; ++rt)
#pragma unroll
        for (int r = 0; r < 4; ++r) {
            const int rowl = rt * 16 + q * 4 + r;
            const hf2 s = split2h(gated[rt][r]);
            const int off = swz(rowl, col * 2, 256);
            *(_Float16*)(sm + SM_IX0 + off) = s.hi;
            *(_Float16*)(sm + SM_IX1 + off) = s.lo;
        }
    __syncthreads();

    mlp_core<false>(sm, wpack + OFF_FW1, wpack + OFF_FW2, wpack + OFF_FWD,
                    b1, flags[R_FB1], b2, flags[R_FB2], bd, flags[R_FBD],
                    r0, out);
}

// ---------------------------------------------------------------------------
extern "C" void kernel_launch(void* const* d_in, const int* in_sizes, int n_in,
                              void* d_out, int out_size, void* d_ws, size_t ws_size,
                              hipStream_t stream)
{
    // ---- resolve input order by size signature (dict order vs sorted) ----
    static const int dictSizes[23] = {8388608, 8388608, 65536, 512, 262144, 512,
                                      32768, 64, 65536, 512, 262144, 512, 32768, 64,
                                      16384, 128, 65536, 512, 262144, 512, 32768, 64, 1};
    static const int dictRole[23]  = {R_X, R_Y, R_SW1, R_SB1, R_SW2, R_SB2, R_SWD, R_SBD,
                                      R_MW1, R_MB1, R_MW2, R_MB2, R_MWD, R_MBD,
                                      R_ATTW, R_ATTB, R_FW1, R_FB1, R_FW2, R_FB2,
                                      R_FWD, R_FBD, -1};
    static const int sortSizes[23] = {128, 16384, 512, 512, 64, 65536, 262144, 32768,
                                      512, 512, 64, 65536, 262144, 32768,
                                      512, 512, 64, 65536, 262144, 32768, 1,
                                      8388608, 8388608};
    static const int sortRole[23]  = {R_ATTB, R_ATTW, R_FB1, R_FB2, R_FBD, R_FW1,
                                      R_FW2, R_FWD, R_MB1, R_MB2, R_MBD, R_MW1,
                                      R_MW2, R_MWD, R_SB1, R_SB2, R_SBD, R_SW1,
                                      R_SW2, R_SWD, -1, R_X, R_Y};
    const void* rp[N_ROLES];
    int rs[N_ROLES];
    for (int i = 0; i < 23 && i < n_in; ++i)
        if (dictRole[i] >= 0) { rp[dictRole[i]] = d_in[i]; rs[dictRole[i]] = in_sizes[i]; }
    {
        bool dictOk = (n_in >= 22);
        for (int i = 0; i < 22 && dictOk; ++i)
            if (in_sizes[i] != dictSizes[i]) dictOk = false;
        if (!dictOk) {
            bool sortOk = (n_in >= 23);
            for (int i = 0; i < 23 && sortOk; ++i)
                if (in_sizes[i] != sortSizes[i]) sortOk = false;
            if (sortOk)
                for (int i = 0; i < 23; ++i)
                    if (sortRole[i] >= 0) { rp[sortRole[i]] = d_in[i]; rs[sortRole[i]] = in_sizes[i]; }
        }
    }

    _Float16* wpack = (_Float16*)d_ws;
    unsigned long long* masks = (unsigned long long*)((char*)d_ws + WS_MASKS);
    int* rrows = (int*)((char*)d_ws + WS_RROWS);
    int* rcnt  = (int*)((char*)d_ws + WS_RCNT);
    int* flags = (int*)((char*)d_ws + WS_FLAGS);

    float* out_f = (float*)d_out;
    float* sub_o = out_f;
    float* mm_o  = out_f + (size_t)BN * 64;
    float* fus_o = out_f + (size_t)2 * BN * 64;

    DetArgs da;
    for (int r = 0; r < N_ROLES; ++r) { da.p[r] = rp[r]; da.n[r] = rs[r]; }
    detect_kernel<<<N_ROLES, 256, 0, stream>>>(da, flags, rcnt);

    PackArgs pa;
    const int prole[10] = {R_SW1, R_SW2, R_SWD, R_MW1, R_MW2, R_MWD,
                           R_FW1, R_FW2, R_FWD, R_ATTW};
    const int Ks[10]   = {128, 512, 512, 128, 512, 512, 128, 512, 512, 128};
    const int Ns[10]   = {512, 512, 64, 512, 512, 64, 512, 512, 64, 128};
    const int offs[10] = {OFF_SW1, OFF_SW2, OFF_SWD, OFF_MW1, OFF_MW2,
                          OFF_MWD, OFF_FW1, OFF_FW2, OFF_FWD, OFF_ATT};
    for (int i = 0; i < 10; ++i) {
        pa.src[i] = rp[prole[i]];
        pa.K[i] = Ks[i];
        pa.N[i] = Ns[i];
        pa.off[i] = offs[i];
        pa.role[i] = prole[i];
    }
    pack_weights<<<dim3(128, 10), 256, 0, stream>>>(pa, wpack, flags);

    sub_mfma<<<BN / MROWS, 512, 0, stream>>>(
        rp[R_X], wpack, rp[R_SB1], rp[R_SB2], rp[R_SBD], flags,
        sub_o, masks, rrows, rcnt);

    rescue_kernel<<<512, 256, 0, stream>>>(
        rp[R_X], rp[R_SW1], rp[R_SB1], rp[R_SW2], rp[R_SB2], rp[R_SWD], rp[R_SBD],
        flags, rrows, rcnt, sub_o, masks);

    mm_mfma<<<BN / MROWS, 512, 0, stream>>>(
        masks, rp[R_Y], wpack, rp[R_MB1], rp[R_MB2], rp[R_MBD], flags, mm_o);

    fusion_mfma<<<BN / MROWS, 512, 0, stream>>>(
        sub_o, mm_o, wpack, rp[R_ATTB], rp[R_FB1], rp[R_FB2], rp[R_FBD],
        flags, fus_o);
}

// Round 7
// 809.151 us; speedup vs baseline: 1.1257x; 1.1257x over previous
//
#include <hip/hip_runtime.h>
#include <math.h>

// ---------------------------------------------------------------------------
// MFMA round, fp16 2-term scheme. fp32 outputs. Per-array dtype detection
// (bf16/fp32/zero). All three MLPs: A split into fp16 hi/lo planes, B rounded
// to a single fp16 plane; a*b ~= alo*b + ahi*b. Top-8 correctness vs fp64
// reference guaranteed by a margin-gated fp64 rescue pass (MARGIN=2e-4,
// validated r6).
// This round: rescue_kernel restructured. (1) LDS 91->74 KB (xs stored fp32 -
// exact, h unpadded broadcast stride, ob aliases xs) -> 2 blocks/CU -> all
// ~460 groups co-resident in ONE wave (was two sequential waves = 2x wall).
// (2) paired-column ownership (2t,2t+1) merges the two per-k weight loads
// into one; #pragma unroll 4 pipelines 4 k-iterations of loads. Per-output
// fp64 accumulation order unchanged -> bitwise-identical rescue results.
// ---------------------------------------------------------------------------

typedef _Float16 halfx8 __attribute__((ext_vector_type(8)));
typedef float    floatx4 __attribute__((ext_vector_type(4)));
#define MFMA16(a,b,c) __builtin_amdgcn_mfma_f32_16x16x32_f16((a),(b),(c),0,0,0)

#define BN 65536
#define MROWS 32
#define MARGIN 2e-4f

// LDS layout (per block, 81920 B total -> 2 blocks/CU on 160 KiB LDS):
//   [0,      8192)  ix hi plane (32 rows x 256 B, swizzled, fp16)
//   [8192,  16384)  ix lo plane
//   [16384, 49152)  h  hi plane (32 rows x 1024 B, swizzled, fp16)
//   [49152, 81920)  h  lo plane
//   outb (SUB only) aliases [0, 8448): 32 x 66 f32 (ix dead after layer 1)
#define SM_IX0 0
#define SM_IX1 8192
#define SM_H0  16384
#define SM_H1  49152
#define SM_BYTES 81920
#define OBST 66

// packed single-plane sizes/offsets (fp16 elements)
#define SZ_W1 65536
#define SZ_W2 262144
#define SZ_WD 32768
#define SZ_ATT 16384
#define OFF_SW1 0
#define OFF_SW2 (OFF_SW1 + SZ_W1)
#define OFF_SWD (OFF_SW2 + SZ_W2)
#define OFF_MW1 (OFF_SWD + SZ_WD)
#define OFF_MW2 (OFF_MW1 + SZ_W1)
#define OFF_MWD (OFF_MW2 + SZ_W2)
#define OFF_FW1 (OFF_MWD + SZ_WD)
#define OFF_FW2 (OFF_FW1 + SZ_W1)
#define OFF_FWD (OFF_FW2 + SZ_W2)
#define OFF_ATT (OFF_FWD + SZ_WD)

// ws byte offsets (pack ends at ~2.2 MB)
#define WS_MASKS (5u << 20)     // BN * 8 B
#define WS_RROWS (6u << 20)     // up to BN ints
#define WS_RCNT  (7u << 20)     // 1 int
#define WS_FLAGS ((7u << 20) + 256)

enum { R_X = 0, R_Y, R_SW1, R_SB1, R_SW2, R_SB2, R_SWD, R_SBD,
       R_MW1, R_MB1, R_MW2, R_MB2, R_MWD, R_MBD, R_ATTW, R_ATTB,
       R_FW1, R_FB1, R_FW2, R_FB2, R_FWD, R_FBD, N_ROLES };

__device__ __forceinline__ float bf2f(unsigned short u) {
    return __uint_as_float((unsigned)u << 16);
}
// fl: 1=bf16, 0=fp32, 2=zero
__device__ __forceinline__ float loadf(const void* p, size_t i, int fl) {
    return fl == 1 ? bf2f(((const unsigned short*)p)[i])
         : fl == 0 ? ((const float*)p)[i] : 0.f;
}
__device__ __forceinline__ double loadd(const void* p, size_t i, int fl) {
    return fl == 1 ? (double)bf2f(((const unsigned short*)p)[i])
         : fl == 0 ? (double)((const float*)p)[i] : 0.0;
}
// compile-time-flag variant: branch-free loop bodies in the rescue kernel
template<int FL>
__device__ __forceinline__ double ldw(const void* p, size_t i) {
    return FL == 1 ? (double)bf2f(((const unsigned short*)p)[i])
         : FL == 0 ? (double)((const float*)p)[i] : 0.0;
}
struct hf2 { _Float16 hi, lo; };
__device__ __forceinline__ hf2 split2h(float v) {
    hf2 r;
    r.hi = (_Float16)v;
    r.lo = (_Float16)(v - (float)r.hi);
    return r;
}
// LDS swizzle: byte offset within a plane; rsB = 256 (ix) or 1024 (h).
__device__ __forceinline__ int swz(int row, int colB, int rsB) {
    return (row * rsB + colB) ^ ((row & 15) << 4);
}

// B-fragment load: 4 nt-tiles (single fp16 plane) for one kt.
__device__ __forceinline__ void ld_b4(const _Float16* __restrict__ p,
                                      int base, int ktn, int kt, int l,
                                      halfx8 (&b)[4])
{
#pragma unroll
    for (int nt = 0; nt < 4; ++nt) {
        const size_t fi = ((((size_t)(base + nt)) * ktn + kt) * 64 + l) * 8;
        b[nt] = *(const halfx8*)(p + fi);
    }
}

// One kt of MFMA work: read A hi/lo frags from LDS, 2-term MFMA into acc.
__device__ __forceinline__ void kt_mfma(const char* __restrict__ sm,
                                        int smA0, int smA1, int rsB,
                                        int kt, int l15, int q,
                                        const halfx8 (&b)[4],
                                        floatx4 (&acc)[2][4])
{
    const int cB = kt * 64 + q * 16;
    halfx8 ahi[2], alo[2];
#pragma unroll
    for (int rt = 0; rt < 2; ++rt) {
        const int off = swz(rt * 16 + l15, cB, rsB);
        ahi[rt] = *(const halfx8*)(sm + smA0 + off);
        alo[rt] = *(const halfx8*)(sm + smA1 + off);
    }
#pragma unroll
    for (int nt = 0; nt < 4; ++nt)
#pragma unroll
        for (int rt = 0; rt < 2; ++rt) {
            acc[rt][nt] = MFMA16(alo[rt], b[nt], acc[rt][nt]);
            acc[rt][nt] = MFMA16(ahi[rt], b[nt], acc[rt][nt]);
        }
}

// ---------------------------------------------------------------------------
// detect: per-array dtype (1=bf16, 0=fp32, 2=zero). Also zeroes rescue count.
// ---------------------------------------------------------------------------
struct DetArgs { const void* p[N_ROLES]; int n[N_ROLES]; };

__global__ __launch_bounds__(256) void detect_kernel(DetArgs da, int* flags, int* rcnt) {
    const int role = blockIdx.x;
    if (role == 0 && threadIdx.x == 0) *rcnt = 0;
    const unsigned short* u = (const unsigned short*)da.p[role];
    int nsamp = da.n[role] / 2;
    if (nsamp > 4096) nsamp = 4096;
    __shared__ int band, nz;
    if (threadIdx.x == 0) { band = 0; nz = 0; }
    __syncthreads();
    int lb = 0, lnz = 0;
    for (int i = threadIdx.x; i < nsamp; i += 256) {
        const unsigned short v = u[2 * i];
        if (v) {
            ++lnz;
            const int e = (v >> 7) & 0xFF;
            if (e >= 100 && e <= 126) ++lb;
        }
    }
    atomicAdd(&band, lb);
    atomicAdd(&nz, lnz);
    __syncthreads();
    if (threadIdx.x == 0)
        flags[role] = (nz == 0) ? 2 : ((band * 2 > nz) ? 1 : 0);
}

// ---------------------------------------------------------------------------
// pack: [K x N] -> MFMA B-frag single fp16 plane. Frag for tile (kt,nt):
// lane l, j=0..7 holds W[kt*32 + (l>>4)*8 + j][nt*16 + (l&15)].
// ---------------------------------------------------------------------------
struct PackArgs { const void* src[10]; int K[10], N[10], off[10], role[10]; };

__global__ __launch_bounds__(256) void pack_weights(PackArgs pa, _Float16* dst,
                                                    const int* __restrict__ flags) {
    const int m = blockIdx.y;
    const int fl = flags[pa.role[m]];
    const int K = pa.K[m], N = pa.N[m];
    const int KT = K >> 5, NT = N >> 4;
    const int total = KT * NT * 64;
    const int t = blockIdx.x * 256 + threadIdx.x;
    if (t >= total) return;
    const int l = t & 63;
    const int idx = t >> 6;            // nt*KT + kt
    const int kt = idx % KT;
    const int nt = idx / KT;
    const int k0 = kt * 32 + ((l >> 4) << 3);
    const int n  = nt * 16 + (l & 15);
    _Float16* dh = dst + pa.off[m] + (size_t)t * 8;
#pragma unroll
    for (int j = 0; j < 8; ++j)
        dh[j] = (_Float16)loadf(pa.src[m], (size_t)(k0 + j) * N + n, fl);
}

// ---------------------------------------------------------------------------
// Core 3-layer MFMA MLP (32 rows, 512 threads = 8 waves, 2 row-tiles/wave).
// fp16 2-term; A from swizzled LDS planes; h in-place; fp32 out.
// ---------------------------------------------------------------------------
template <bool SUB>
__device__ __forceinline__ void mlp_core(
    char* __restrict__ sm,
    const _Float16* __restrict__ p1,
    const _Float16* __restrict__ p2,
    const _Float16* __restrict__ pd,
    const void* __restrict__ b1, int fb1,
    const void* __restrict__ b2, int fb2,
    const void* __restrict__ bd, int fbd,
    int r0, float* __restrict__ out)
{
    const int tid = threadIdx.x;
    const int l = tid & 63, w = tid >> 6, l15 = l & 15, q = l >> 4;

    // ---- layer 1: K=128, N=512; wave w owns 64-col slab; 2 row-tiles ----
    floatx4 acc[2][4];
#pragma unroll
    for (int rt = 0; rt < 2; ++rt)
#pragma unroll
        for (int nt = 0; nt < 4; ++nt) acc[rt][nt] = (floatx4)0.0f;
#pragma unroll
    for (int kt = 0; kt < 4; ++kt) {
        halfx8 B[4];
        ld_b4(p1, w * 4, 4, kt, l, B);
        kt_mfma(sm, SM_IX0, SM_IX1, 256, kt, l15, q, B, acc);
    }
#pragma unroll
    for (int nt = 0; nt < 4; ++nt) {
        const int col = w * 64 + nt * 16 + l15;
        const float bias = loadf(b1, col, fb1);
#pragma unroll
        for (int rt = 0; rt < 2; ++rt)
#pragma unroll
            for (int r = 0; r < 4; ++r) {
                const int row = rt * 16 + q * 4 + r;
                float v = acc[rt][nt][r] + bias;
                v = v > 0.f ? v : 0.f;
                const hf2 s = split2h(v);
                const int o = swz(row, col * 2, 1024);
                *(_Float16*)(sm + SM_H0 + o) = s.hi;
                *(_Float16*)(sm + SM_H1 + o) = s.lo;
            }
    }
    __syncthreads();

    // ---- layer 2: K=512, in-place ----
    floatx4 acc2[2][4];
#pragma unroll
    for (int rt = 0; rt < 2; ++rt)
#pragma unroll
        for (int nt = 0; nt < 4; ++nt) acc2[rt][nt] = (floatx4)0.0f;
    for (int kt = 0; kt < 16; ++kt) {
        halfx8 B[4];
        ld_b4(p2, w * 4, 16, kt, l, B);
        kt_mfma(sm, SM_H0, SM_H1, 1024, kt, l15, q, B, acc2);
    }
    __syncthreads();  // all reads of h done before overwrite
#pragma unroll
    for (int nt = 0; nt < 4; ++nt) {
        const int col = w * 64 + nt * 16 + l15;
        const float bias = loadf(b2, col, fb2);
#pragma unroll
        for (int rt = 0; rt < 2; ++rt)
#pragma unroll
            for (int r = 0; r < 4; ++r) {
                const int row = rt * 16 + q * 4 + r;
                float v = acc2[rt][nt][r] + bias;
                v = v > 0.f ? v : 0.f;
                const hf2 s = split2h(v);
                const int o = swz(row, col * 2, 1024);
                *(_Float16*)(sm + SM_H0 + o) = s.hi;
                *(_Float16*)(sm + SM_H1 + o) = s.lo;
            }
    }
    __syncthreads();

    // ---- layer 3: K=512, N=64; 8 waves: nt=w&3, rt=w>>2 ----
    {
        const int nt3 = w & 3, rt3 = w >> 2;
        floatx4 a3 = (floatx4)0.0f;
        for (int kt = 0; kt < 16; ++kt) {
            const size_t fi = (((size_t)(nt3 * 16 + kt)) * 64 + l) * 8;
            const halfx8 b = *(const halfx8*)(pd + fi);
            const int off = swz(rt3 * 16 + l15, kt * 64 + q * 16, 1024);
            const halfx8 ahi = *(const halfx8*)(sm + SM_H0 + off);
            const halfx8 alo = *(const halfx8*)(sm + SM_H1 + off);
            a3 = MFMA16(alo, b, a3);
            a3 = MFMA16(ahi, b, a3);
        }
        const int col = nt3 * 16 + l15;
        const float bias = loadf(bd, col, fbd);
        float* outb = (float*)sm;  // aliases ix region (dead after L1)
#pragma unroll
        for (int r = 0; r < 4; ++r) {
            const int row = rt3 * 16 + q * 4 + r;
            const float v = a3[r] + bias;  // no relu on output layer
            out[(size_t)(r0 + row) * 64 + col] = v;
            if (SUB) outb[row * OBST + col] = v;
        }
    }
    if (SUB) __syncthreads();
}

// ---------------------------------------------------------------------------
// K1: sub MLP + per-row top-8 mask + margin-gated rescue list.
// ---------------------------------------------------------------------------
__global__ __launch_bounds__(512, 4)
void sub_mfma(const void* __restrict__ x, const _Float16* __restrict__ wpack,
              const void* __restrict__ b1, const void* __restrict__ b2,
              const void* __restrict__ bd, const int* __restrict__ flags,
              float* __restrict__ out, unsigned long long* __restrict__ masks,
              int* __restrict__ rrows, int* __restrict__ rcnt)
{
    __shared__ __align__(16) char sm[SM_BYTES];
    const int fx = flags[R_X];
    const int r0 = blockIdx.x * MROWS;

    for (int i = threadIdx.x; i < MROWS * 128; i += 512) {
        const int r = i >> 7, c = i & 127;
        const hf2 s = split2h(loadf(x, (size_t)(r0 + r) * 128 + c, fx));
        const int off = swz(r, c * 2, 256);
        *(_Float16*)(sm + SM_IX0 + off) = s.hi;
        *(_Float16*)(sm + SM_IX1 + off) = s.lo;
    }
    __syncthreads();

    mlp_core<true>(sm, wpack + OFF_SW1, wpack + OFF_SW2, wpack + OFF_SWD,
                   b1, flags[R_SB1], b2, flags[R_SB2], bd, flags[R_SBD],
                   r0, out);

    // top-9 per row (strict '>' insertion: jax tie rule -> lowest index wins)
    if (threadIdx.x < MROWS) {
        const float* rowp = (const float*)sm + threadIdx.x * OBST;
        float vals[9];
        int idxs[9];
#pragma unroll
        for (int j = 0; j < 9; ++j) { vals[j] = -__builtin_inff(); idxs[j] = 0; }
        for (int i = 0; i < 64; ++i) {
            const float v = rowp[i];
            if (v > vals[8]) {
                int p = 8;
                while (p > 0 && v > vals[p - 1]) {
                    vals[p] = vals[p - 1];
                    idxs[p] = idxs[p - 1];
                    --p;
                }
                vals[p] = v;
                idxs[p] = i;
            }
        }
        unsigned long long m = 0ull;
#pragma unroll
        for (int j = 0; j < 8; ++j) m |= (1ull << idxs[j]);
        masks[r0 + threadIdx.x] = m;
        if (vals[7] - vals[8] < MARGIN) {
            const int slot = atomicAdd(rcnt, 1);
            rrows[slot] = r0 + threadIdx.x;
        }
    }
}

// ---------------------------------------------------------------------------
// K1b: fp64 rescue for marginal rows — recompute sub rows exactly, fix mask
// and out_sub rows. 16 rows/block-group; xs staged fp32 (exact), h fp64
// unpadded (broadcast reads), ob aliases xs. LDS 74048 B -> 2 blocks/CU so
// all groups are co-resident in one wave. Thread owns cols (2t, 2t+1) ->
// the two per-k weight loads merge; k-loops unrolled x4 to pipeline loads.
// Per-output fp64 accumulation order identical to the validated version.
// ---------------------------------------------------------------------------
#define RPB 16
#define OBST2 66

// L1/L2: 256 threads own cols (2t, 2t+1); accumulate 16 rows each.
template<int FL, int K, int S, typename TI>
__device__ __forceinline__ void r_layer12(const void* __restrict__ W,
                                          const TI* __restrict__ in,
                                          double* __restrict__ a0,
                                          double* __restrict__ a1, int t)
{
#pragma unroll 4
    for (int k = 0; k < K; ++k) {
        const double w0 = ldw<FL>(W, (size_t)k * 512 + 2 * t);
        const double w1 = ldw<FL>(W, (size_t)k * 512 + 2 * t + 1);
#pragma unroll
        for (int r = 0; r < RPB; ++r) {
            const double xv = (double)in[r * S + k];
            a0[r] = fma(xv, w0, a0[r]);
            a1[r] = fma(xv, w1, a1[r]);
        }
    }
}

// L3: thread owns col c = t&63, row-group rg = t>>6 (4 rows).
template<int FL>
__device__ __forceinline__ void r_layer3(const void* __restrict__ W,
                                         const double* __restrict__ h,
                                         int c, int rg, double* __restrict__ a)
{
#pragma unroll 4
    for (int k = 0; k < 512; ++k) {
        const double w = ldw<FL>(W, (size_t)k * 64 + c);
#pragma unroll
        for (int j = 0; j < 4; ++j)
            a[j] = fma(h[(rg * 4 + j) * 512 + k], w, a[j]);
    }
}

#define R_DISPATCH(fl, CALL)                                   \
    do {                                                       \
        if ((fl) == 1)      { CALL(1); }                       \
        else if ((fl) == 0) { CALL(0); }                       \
        else                { CALL(2); }                       \
    } while (0)

__global__ __launch_bounds__(256)
void rescue_kernel(const void* __restrict__ x,
                   const void* __restrict__ W1, const void* __restrict__ b1,
                   const void* __restrict__ W2, const void* __restrict__ b2,
                   const void* __restrict__ Wd, const void* __restrict__ bd,
                   const int* __restrict__ flags,
                   const int* __restrict__ rrows, const int* __restrict__ rcnt,
                   float* __restrict__ out, unsigned long long* __restrict__ masks)
{
    __shared__ int rowids[RPB];
    __shared__ __align__(16) char xob[RPB * OBST2 * 8];   // xs f32 (8192) / ob f64 (8448) union
    __shared__ __align__(16) double hsm[RPB * 512];       // 65536 B
    float* xs = (float*)xob;
    double* ob = (double*)xob;
    const int fx = flags[R_X], f1 = flags[R_SW1], fb1 = flags[R_SB1],
              f2 = flags[R_SW2], fb2 = flags[R_SB2],
              f3 = flags[R_SWD], fb3 = flags[R_SBD];
    const int t = threadIdx.x;
    const int n = *rcnt;

    for (int g = blockIdx.x; g * RPB < n; g += gridDim.x) {
        const int base = g * RPB;
        int cnt = n - base;
        if (cnt > RPB) cnt = RPB;
        if (t < RPB) rowids[t] = rrows[base + (t < cnt ? t : cnt - 1)];
        __syncthreads();

        // stage inputs (fp32 in LDS; fp64 conversion on read is exact)
        for (int i = t; i < RPB * 128; i += 256) {
            const int r = i >> 7, c = i & 127;
            xs[r * 128 + c] = loadf(x, (size_t)rowids[r] * 128 + c, fx);
        }
        __syncthreads();

        // ---- L1: K=128 ----
        {
            double a0[RPB], a1[RPB];
#pragma unroll
            for (int r = 0; r < RPB; ++r) { a0[r] = 0.0; a1[r] = 0.0; }
#define L1_CALL(FL) r_layer12<FL, 128, 128, float>(W1, xs, a0, a1, t)
            R_DISPATCH(f1, L1_CALL);
#undef L1_CALL
            const double bb0 = loadd(b1, 2 * t, fb1), bb1 = loadd(b1, 2 * t + 1, fb1);
#pragma unroll
            for (int r = 0; r < RPB; ++r) {
                const double v0 = a0[r] + bb0, v1 = a1[r] + bb1;
                hsm[r * 512 + 2 * t]     = v0 > 0.0 ? v0 : 0.0;
                hsm[r * 512 + 2 * t + 1] = v1 > 0.0 ? v1 : 0.0;
            }
        }
        __syncthreads();

        // ---- L2: K=512, in-place (accumulate fully, then overwrite) ----
        {
            double a0[RPB], a1[RPB];
#pragma unroll
            for (int r = 0; r < RPB; ++r) { a0[r] = 0.0; a1[r] = 0.0; }
#define L2_CALL(FL) r_layer12<FL, 512, 512, double>(W2, hsm, a0, a1, t)
            R_DISPATCH(f2, L2_CALL);
#undef L2_CALL
            __syncthreads();  // all reads of h done before overwrite
            const double bb0 = loadd(b2, 2 * t, fb2), bb1 = loadd(b2, 2 * t + 1, fb2);
#pragma unroll
            for (int r = 0; r < RPB; ++r) {
                const double v0 = a0[r] + bb0, v1 = a1[r] + bb1;
                hsm[r * 512 + 2 * t]     = v0 > 0.0 ? v0 : 0.0;
                hsm[r * 512 + 2 * t + 1] = v1 > 0.0 ? v1 : 0.0;
            }
        }
        __syncthreads();

        // ---- L3: K=512, N=64; col c, 4 rows per thread ----
        {
            const int c = t & 63, rg = t >> 6;
            double a[4];
#pragma unroll
            for (int j = 0; j < 4; ++j) a[j] = 0.0;
#define L3_CALL(FL) r_layer3<FL>(Wd, hsm, c, rg, a)
            R_DISPATCH(f3, L3_CALL);
#undef L3_CALL
            const double bb = loadd(bd, c, fb3);
#pragma unroll
            for (int j = 0; j < 4; ++j) {
                const int r = rg * 4 + j;
                const double v = a[j] + bb;
                ob[r * OBST2 + c] = v;
                if (r < cnt) out[(size_t)rowids[r] * 64 + c] = (float)v;
            }
        }
        __syncthreads();

        // ---- top-8 per valid row (strict '>' insertion, as before) ----
        if (t < cnt) {
            double vals[8];
            int idxs[8];
#pragma unroll
            for (int j = 0; j < 8; ++j) { vals[j] = -1.0e300; idxs[j] = 0; }
            for (int i = 0; i < 64; ++i) {
                const double v = ob[t * OBST2 + i];
                if (v > vals[7]) {
                    int p = 7;
                    while (p > 0 && v > vals[p - 1]) {
                        vals[p] = vals[p - 1];
                        idxs[p] = idxs[p - 1];
                        --p;
                    }
                    vals[p] = v;
                    idxs[p] = i;
                }
            }
            unsigned long long m = 0ull;
#pragma unroll
            for (int j = 0; j < 8; ++j) m |= (1ull << idxs[j]);
            masks[rowids[t]] = m;
        }
        __syncthreads();  // ob/rowids/xs reused next iteration
    }
}

// ---------------------------------------------------------------------------
// K2: mm MLP from masked y.
// ---------------------------------------------------------------------------
__global__ __launch_bounds__(512, 4)
void mm_mfma(const unsigned long long* __restrict__ masks,
             const void* __restrict__ y, const _Float16* __restrict__ wpack,
             const void* __restrict__ b1, const void* __restrict__ b2,
             const void* __restrict__ bd, const int* __restrict__ flags,
             float* __restrict__ out)
{
    __shared__ __align__(16) char sm[SM_BYTES];
    const int fy = flags[R_Y];
    const int r0 = blockIdx.x * MROWS;

    for (int i = threadIdx.x; i < MROWS * 128; i += 512) {
        const int r = i >> 7, c = i & 127;
        const bool keep = (masks[r0 + r] >> (c >> 1)) & 1ull;
        const float v = keep ? loadf(y, (size_t)(r0 + r) * 128 + c, fy) : 0.f;
        const hf2 s = split2h(v);
        const int off = swz(r, c * 2, 256);
        *(_Float16*)(sm + SM_IX0 + off) = s.hi;
        *(_Float16*)(sm + SM_IX1 + off) = s.lo;
    }
    __syncthreads();

    mlp_core<false>(sm, wpack + OFF_MW1, wpack + OFF_MW2, wpack + OFF_MWD,
                    b1, flags[R_MB1], b2, flags[R_MB2], bd, flags[R_MBD],
                    r0, out);
}

// ---------------------------------------------------------------------------
// K3: cat (fp32 from d_out) -> sigmoid attention gate -> fusion MLP.
// ---------------------------------------------------------------------------
__global__ __launch_bounds__(512, 4)
void fusion_mfma(const float* __restrict__ subf, const float* __restrict__ mmf,
                 const _Float16* __restrict__ wpack,
                 const void* __restrict__ attb,
                 const void* __restrict__ b1, const void* __restrict__ b2,
                 const void* __restrict__ bd, const int* __restrict__ flags,
                 float* __restrict__ out)
{
    __shared__ __align__(16) char sm[SM_BYTES];
    const int tid = threadIdx.x;
    const int l = tid & 63, w = tid >> 6, l15 = l & 15, q = l >> 4;
    const int r0 = blockIdx.x * MROWS;

    for (int i = tid; i < MROWS * 128; i += 512) {
        const int r = i >> 7, c = i & 127;
        const size_t row = (size_t)(r0 + r);
        const float v = (c < 64) ? subf[row * 64 + c] : mmf[row * 64 + (c - 64)];
        const hf2 s = split2h(v);
        const int off = swz(r, c * 2, 256);
        *(_Float16*)(sm + SM_IX0 + off) = s.hi;
        *(_Float16*)(sm + SM_IX1 + off) = s.lo;
    }
    __syncthreads();

    // attention: N=128, wave w owns 16-col tile nt=w; 2 row-tiles; 2-term
    floatx4 aacc[2];
    aacc[0] = (floatx4)0.0f;
    aacc[1] = (floatx4)0.0f;
    const _Float16* patt = wpack + OFF_ATT;
#pragma unroll
    for (int kt = 0; kt < 4; ++kt) {
        const size_t fi = (((size_t)(w * 4 + kt)) * 64 + l) * 8;
        const halfx8 b = *(const halfx8*)(patt + fi);
        const int cB = kt * 64 + q * 16;
#pragma unroll
        for (int rt = 0; rt < 2; ++rt) {
            const int off = swz(rt * 16 + l15, cB, 256);
            const halfx8 ahi = *(const halfx8*)(sm + SM_IX0 + off);
            const halfx8 alo = *(const halfx8*)(sm + SM_IX1 + off);
            aacc[rt] = MFMA16(alo, b, aacc[rt]);
            aacc[rt] = MFMA16(ahi, b, aacc[rt]);
        }
    }
    const int col = w * 16 + l15;
    const float ab = loadf(attb, col, flags[R_ATTB]);
    float gated[2][4];
#pragma unroll
    for (int rt = 0; rt < 2; ++rt)
#pragma unroll
        for (int r = 0; r < 4; ++r) {
            const int rowl = rt * 16 + q * 4 + r;
            const float pre = aacc[rt][r] + ab;
            const float s = 1.f / (1.f + expf(-pre));
            const int off = swz(rowl, col * 2, 256);
            const float catv = (float)*(const _Float16*)(sm + SM_IX0 + off)
                             + (float)*(const _Float16*)(sm + SM_IX1 + off);
            gated[rt][r] = catv * s;
        }
    __syncthreads();  // all attention reads of ix done
#pragma unroll
    for (int rt = 0; rt < 2; ++rt)
#pragma unroll
        for (int r = 0; r < 4; ++r) {
            const int rowl = rt * 16 + q * 4 + r;
            const hf2 s = split2h(gated[rt][r]);
            const int off = swz(rowl, col * 2, 256);
            *(_Float16*)(sm + SM_IX0 + off) = s.hi;
            *(_Float16*)(sm + SM_IX1 + off) = s.lo;
        }
    __syncthreads();

    mlp_core<false>(sm, wpack + OFF_FW1, wpack + OFF_FW2, wpack + OFF_FWD,
                    b1, flags[R_FB1], b2, flags[R_FB2], bd, flags[R_FBD],
                    r0, out);
}

// ---------------------------------------------------------------------------
extern "C" void kernel_launch(void* const* d_in, const int* in_sizes, int n_in,
                              void* d_out, int out_size, void* d_ws, size_t ws_size,
                              hipStream_t stream)
{
    // ---- resolve input order by size signature (dict order vs sorted) ----
    static const int dictSizes[23] = {8388608, 8388608, 65536, 512, 262144, 512,
                                      32768, 64, 65536, 512, 262144, 512, 32768, 64,
                                      16384, 128, 65536, 512, 262144, 512, 32768, 64, 1};
    static const int dictRole[23]  = {R_X, R_Y, R_SW1, R_SB1, R_SW2, R_SB2, R_SWD, R_SBD,
                                      R_MW1, R_MB1, R_MW2, R_MB2, R_MWD, R_MBD,
                                      R_ATTW, R_ATTB, R_FW1, R_FB1, R_FW2, R_FB2,
                                      R_FWD, R_FBD, -1};
    static const int sortSizes[23] = {128, 16384, 512, 512, 64, 65536, 262144, 32768,
                                      512, 512, 64, 65536, 262144, 32768,
                                      512, 512, 64, 65536, 262144, 32768, 1,
                                      8388608, 8388608};
    static const int sortRole[23]  = {R_ATTB, R_ATTW, R_FB1, R_FB2, R_FBD, R_FW1,
                                      R_FW2, R_FWD, R_MB1, R_MB2, R_MBD, R_MW1,
                                      R_MW2, R_MWD, R_SB1, R_SB2, R_SBD, R_SW1,
                                      R_SW2, R_SWD, -1, R_X, R_Y};
    const void* rp[N_ROLES];
    int rs[N_ROLES];
    for (int i = 0; i < 23 && i < n_in; ++i)
        if (dictRole[i] >= 0) { rp[dictRole[i]] = d_in[i]; rs[dictRole[i]] = in_sizes[i]; }
    {
        bool dictOk = (n_in >= 22);
        for (int i = 0; i < 22 && dictOk; ++i)
            if (in_sizes[i] != dictSizes[i]) dictOk = false;
        if (!dictOk) {
            bool sortOk = (n_in >= 23);
            for (int i = 0; i < 23 && sortOk; ++i)
                if (in_sizes[i] != sortSizes[i]) sortOk = false;
            if (sortOk)
                for (int i = 0; i < 23; ++i)
                    if (sortRole[i] >= 0) { rp[sortRole[i]] = d_in[i]; rs[sortRole[i]] = in_sizes[i]; }
        }
    }

    _Float16* wpack = (_Float16*)d_ws;
    unsigned long long* masks = (unsigned long long*)((char*)d_ws + WS_MASKS);
    int* rrows = (int*)((char*)d_ws + WS_RROWS);
    int* rcnt  = (int*)((char*)d_ws + WS_RCNT);
    int* flags = (int*)((char*)d_ws + WS_FLAGS);

    float* out_f = (float*)d_out;
    float* sub_o = out_f;
    float* mm_o  = out_f + (size_t)BN * 64;
    float* fus_o = out_f + (size_t)2 * BN * 64;

    DetArgs da;
    for (int r = 0; r < N_ROLES; ++r) { da.p[r] = rp[r]; da.n[r] = rs[r]; }
    detect_kernel<<<N_ROLES, 256, 0, stream>>>(da, flags, rcnt);

    PackArgs pa;
    const int prole[10] = {R_SW1, R_SW2, R_SWD, R_MW1, R_MW2, R_MWD,
                           R_FW1, R_FW2, R_FWD, R_ATTW};
    const int Ks[10]   = {128, 512, 512, 128, 512, 512, 128, 512, 512, 128};
    const int Ns[10]   = {512, 512, 64, 512, 512, 64, 512, 512, 64, 128};
    const int offs[10] = {OFF_SW1, OFF_SW2, OFF_SWD, OFF_MW1, OFF_MW2,
                          OFF_MWD, OFF_FW1, OFF_FW2, OFF_FWD, OFF_ATT};
    for (int i = 0; i < 10; ++i) {
        pa.src[i] = rp[prole[i]];
        pa.K[i] = Ks[i];
        pa.N[i] = Ns[i];
        pa.off[i] = offs[i];
        pa.role[i] = prole[i];
    }
    pack_weights<<<dim3(128, 10), 256, 0, stream>>>(pa, wpack, flags);

    sub_mfma<<<BN / MROWS, 512, 0, stream>>>(
        rp[R_X], wpack, rp[R_SB1], rp[R_SB2], rp[R_SBD], flags,
        sub_o, masks, rrows, rcnt);

    rescue_kernel<<<512, 256, 0, stream>>>(
        rp[R_X], rp[R_SW1], rp[R_SB1], rp[R_SW2], rp[R_SB2], rp[R_SWD], rp[R_SBD],
        flags, rrows, rcnt, sub_o, masks);

    mm_mfma<<<BN / MROWS, 512, 0, stream>>>(
        masks, rp[R_Y], wpack, rp[R_MB1], rp[R_MB2], rp[R_MBD], flags, mm_o);

    fusion_mfma<<<BN / MROWS, 512, 0, stream>>>(
        sub_o, mm_o, wpack, rp[R_ATTB], rp[R_FB1], rp[R_FB2], rp[R_FBD],
        flags, fus_o);
}